// Round 1
// baseline (67.919 us; speedup 1.0000x reference)
//
#include <hip/hip_runtime.h>
#include <hip/hip_bf16.h>

#define N_ROWS 256
#define IN_F   2048
#define OUT_F  128
#define KD     32
#define OUT_COLS (IN_F + OUT_F)   // 2176
#define MT_COLS  4096             // OUT_F * KD

typedef __bf16 bf16x8 __attribute__((ext_vector_type(8)));
typedef __bf16 bf16x4 __attribute__((ext_vector_type(4)));
typedef float  f32x4  __attribute__((ext_vector_type(4)));

// ---------------------------------------------------------------------------
// Kernel 1: Mt[o][n] = sum_k x[n][k] * T[k][o]   (o in [0,4096), n in [0,256))
// Tile: BM=64 (n-rows), BN=32 (o-cols), BK=32.  grid = (4096/32, 256/64) = (128,4)
// 256 threads = 4 waves; wave w owns rows [w*16, w*16+16): 1 m-frag x 2 n-frags.
// MFMA lane mapping (16x16x32 bf16):
//   A: lane l holds A[l&15][(l>>4)*8 + i], i=0..7
//   B: lane l holds B[(l>>4)*8 + i][l&15]
//   D: lane l, reg r holds D[(l>>4)*4 + r][l&15]   (verified m89/m91)
// ---------------------------------------------------------------------------
__global__ __launch_bounds__(256, 2) void gemm_kernel(const float* __restrict__ x,
                                                      const float* __restrict__ Tm,
                                                      float* __restrict__ Mt) {
    __shared__ __bf16 As[64][32];     // bf16, row stride 64 B
    __shared__ float  Bs[32][33];     // f32, +1 pad -> conflict-free frag reads

    const int n0  = blockIdx.x * 32;  // o-tile base
    const int m0  = blockIdx.y * 64;  // n-tile base
    const int tid = threadIdx.x;
    const int lane = tid & 63;
    const int wid  = tid >> 6;
    const int fr = lane & 15;
    const int fg = lane >> 4;         // 0..3

    f32x4 acc[2] = {};

    for (int kt = 0; kt < IN_F / 32; ++kt) {
        __syncthreads();
        // stage A: 64x32 f32 -> bf16 LDS (2 float4 per thread)
        #pragma unroll
        for (int r = 0; r < 2; ++r) {
            int q   = tid + r * 256;        // float4 index 0..511
            int row = q >> 3;               // 0..63
            int kc  = (q & 7) << 2;         // 0,4,..,28
            float4 v = *reinterpret_cast<const float4*>(&x[(m0 + row) * IN_F + kt * 32 + kc]);
            bf16x4 t4 = { (__bf16)v.x, (__bf16)v.y, (__bf16)v.z, (__bf16)v.w };
            *reinterpret_cast<bf16x4*>(&As[row][kc]) = t4;
        }
        // stage B: 32x32 f32 (1 float4 per thread)
        {
            int kk = tid >> 3;              // 0..31
            int nc = (tid & 7) << 2;        // 0,4,..,28
            float4 v = *reinterpret_cast<const float4*>(&Tm[(kt * 32 + kk) * MT_COLS + n0 + nc]);
            Bs[kk][nc]     = v.x;
            Bs[kk][nc + 1] = v.y;
            Bs[kk][nc + 2] = v.z;
            Bs[kk][nc + 3] = v.w;
        }
        __syncthreads();

        bf16x8 a = *reinterpret_cast<const bf16x8*>(&As[wid * 16 + fr][fg * 8]);
        #pragma unroll
        for (int ni = 0; ni < 2; ++ni) {
            bf16x8 b;
            #pragma unroll
            for (int i = 0; i < 8; ++i)
                b[i] = (__bf16)Bs[fg * 8 + i][ni * 16 + fr];
            acc[ni] = __builtin_amdgcn_mfma_f32_16x16x32_bf16(a, b, acc[ni], 0, 0, 0);
        }
    }

    // epilogue: transposed write Mt[o][n]; lane's 4 regs are 4 consecutive n -> float4
    #pragma unroll
    for (int ni = 0; ni < 2; ++ni) {
        int o     = n0 + ni * 16 + fr;
        int nbase = m0 + wid * 16 + fg * 4;
        *reinterpret_cast<f32x4*>(&Mt[o * N_ROWS + nbase]) = acc[ni];
    }
}

// ---------------------------------------------------------------------------
// Kernel 2: o_b[j,f] = sum_i exp(-sum_d |M[i,f,d] - M[j,f,d]|)
// grid = (128 f, 4 j-quarters); 256 threads = 4 waves.
// Wave w handles i in [w*64, w*64+64); lane = local j (64 j per block-quarter).
// Mf[i][d] staged in LDS ([256][36] padded); inner reads are wave-uniform
// (broadcast) so conflict-free.
// ---------------------------------------------------------------------------
__global__ __launch_bounds__(256, 2) void pairwise_kernel(const float* __restrict__ Mt,
                                                          float* __restrict__ out) {
    __shared__ float Mf[256][36];
    __shared__ float part[4][64];

    const int f   = blockIdx.x;   // 0..127
    const int jq  = blockIdx.y;   // 0..3
    const int tid = threadIdx.x;
    const int lane = tid & 63;
    const int wid  = tid >> 6;

    // stage Mf[i][d] = Mt[f*32+d][i]; coalesced global reads (lane-consecutive i)
    {
        float tmp[32];
        #pragma unroll
        for (int d = 0; d < 32; ++d)
            tmp[d] = Mt[(f * KD + d) * N_ROWS + tid];
        #pragma unroll
        for (int d4 = 0; d4 < 8; ++d4) {
            f32x4 v = { tmp[d4 * 4], tmp[d4 * 4 + 1], tmp[d4 * 4 + 2], tmp[d4 * 4 + 3] };
            *reinterpret_cast<f32x4*>(&Mf[tid][d4 * 4]) = v;
        }
    }
    __syncthreads();

    const int j = jq * 64 + lane;
    float mj[32];
    #pragma unroll
    for (int d4 = 0; d4 < 8; ++d4) {
        f32x4 v = *reinterpret_cast<const f32x4*>(&Mf[j][d4 * 4]);
        mj[d4 * 4]     = v[0];
        mj[d4 * 4 + 1] = v[1];
        mj[d4 * 4 + 2] = v[2];
        mj[d4 * 4 + 3] = v[3];
    }

    float acc = 0.f;
    const int i0 = wid * 64;
    for (int ii = 0; ii < 64; ++ii) {
        const int i = i0 + ii;
        float norm = 0.f;
        #pragma unroll
        for (int d4 = 0; d4 < 8; ++d4) {
            f32x4 v = *reinterpret_cast<const f32x4*>(&Mf[i][d4 * 4]);
            norm += fabsf(v[0] - mj[d4 * 4]);
            norm += fabsf(v[1] - mj[d4 * 4 + 1]);
            norm += fabsf(v[2] - mj[d4 * 4 + 2]);
            norm += fabsf(v[3] - mj[d4 * 4 + 3]);
        }
        acc += __expf(-norm);
    }

    part[wid][lane] = acc;
    __syncthreads();
    if (tid < 64) {
        float s = part[0][tid] + part[1][tid] + part[2][tid] + part[3][tid];
        int jj = jq * 64 + tid;
        out[jj * OUT_COLS + IN_F + f] = s;
    }
}

// ---------------------------------------------------------------------------
// Kernel 3: copy x into out[:, 0:2048]
// ---------------------------------------------------------------------------
__global__ __launch_bounds__(256) void copy_kernel(const float* __restrict__ x,
                                                   float* __restrict__ out) {
    const int row = blockIdx.x;
    const int c   = threadIdx.x * 8;
    float4 v0 = *reinterpret_cast<const float4*>(&x[row * IN_F + c]);
    float4 v1 = *reinterpret_cast<const float4*>(&x[row * IN_F + c + 4]);
    *reinterpret_cast<float4*>(&out[row * OUT_COLS + c])     = v0;
    *reinterpret_cast<float4*>(&out[row * OUT_COLS + c + 4]) = v1;
}

extern "C" void kernel_launch(void* const* d_in, const int* in_sizes, int n_in,
                              void* d_out, int out_size, void* d_ws, size_t ws_size,
                              hipStream_t stream) {
    const float* x  = (const float*)d_in[0];   // [256, 2048] f32
    const float* Tm = (const float*)d_in[1];   // [2048, 128, 32] f32
    float* out = (float*)d_out;                // [256, 2176] f32
    float* Mt  = (float*)d_ws;                 // [4096, 256] f32 = 4 MB scratch

    gemm_kernel<<<dim3(128, 4), 256, 0, stream>>>(x, Tm, Mt);
    copy_kernel<<<dim3(256), 256, 0, stream>>>(x, out);
    pairwise_kernel<<<dim3(128, 4), 256, 0, stream>>>(Mt, out);
}

// Round 2
// 40.929 us; speedup vs baseline: 1.6594x; 1.6594x over previous
//
#include <hip/hip_runtime.h>
#include <hip/hip_bf16.h>
#include <stdint.h>

#define N_ROWS 256
#define IN_F   2048
#define OUT_F  128
#define KD     32
#define OUT_COLS 2176
#define O_DIM  4096              // OUT_F * KD

typedef __bf16 bf16x8 __attribute__((ext_vector_type(8)));
typedef float  f32x4  __attribute__((ext_vector_type(4)));

#define AS_BYTES 32768           // per K-step: 256 n x 64 k bf16 (XOR-swizzled image)
#define BS_BYTES 8192            // per K-step: 64 k x 32 o f32 (linear)
#define BUF_BYTES (AS_BYTES + BS_BYTES)
#define NBUF 3
#define LDS_TOTAL (BUF_BYTES * NBUF)   // 122880 B

// ---------------------------------------------------------------------------
// Prep: (a) copy x into out[:, 0:2048]; (b) write xb = bf16(x) in the
// pre-swizzled per-k-tile LDS image layout expected by gemm's global_load_lds:
//   xb byte offset = kt*32768 + n*128 + slot*16, containing
//   x[n][kt*64 + ((slot ^ (n&7))<<3) .. +8] as bf16x8.
// ---------------------------------------------------------------------------
__global__ __launch_bounds__(256) void prep_kernel(const float* __restrict__ x,
                                                   float* __restrict__ out,
                                                   __bf16* __restrict__ xb) {
    const int q    = blockIdx.x * 256 + threadIdx.x;   // 0..65535
    const int kt   = q >> 11;                          // 0..31
    const int n    = (q >> 3) & 255;
    const int slot = q & 7;
    const int k0   = kt * 64 + ((slot ^ (n & 7)) << 3);

    const float* src = &x[n * IN_F + k0];
    float4 v0 = *reinterpret_cast<const float4*>(src);
    float4 v1 = *reinterpret_cast<const float4*>(src + 4);

    *reinterpret_cast<float4*>(&out[n * OUT_COLS + k0])     = v0;
    *reinterpret_cast<float4*>(&out[n * OUT_COLS + k0 + 4]) = v1;

    bf16x8 p = { (__bf16)v0.x, (__bf16)v0.y, (__bf16)v0.z, (__bf16)v0.w,
                 (__bf16)v1.x, (__bf16)v1.y, (__bf16)v1.z, (__bf16)v1.w };
    *reinterpret_cast<bf16x8*>(&xb[kt * 16384 + n * 64 + slot * 8]) = p;
}

// ---------------------------------------------------------------------------
// GEMM: Mt[o][n] = sum_k x[n][k] * T[k][o], split-K over blockIdx.y.
// Block: 512 threads (8 waves = 4 m-groups x 2 o-groups), BM=256, BO=32, BK=64.
// 3-deep global_load_lds pipeline, counted vmcnt(5), one s_barrier per K-step.
// ---------------------------------------------------------------------------
__global__ __launch_bounds__(512, 2) void gemm_kernel(const __bf16* __restrict__ xb,
                                                      const float* __restrict__ Tm,
                                                      float* __restrict__ MtBase,
                                                      int kspan) {
    extern __shared__ char smem[];
    const int tid   = threadIdx.x;
    const int lane  = tid & 63;
    const int wid   = tid >> 6;          // 0..7
    const int o0    = blockIdx.x * 32;
    const int khalf = blockIdx.y;
    const int kt0   = (khalf * kspan) >> 6;   // starting global k-tile
    const int nk    = kspan >> 6;
    float* dst = MtBase + (size_t)khalf * O_DIM * N_ROWS;

    const int fr = lane & 15;
    const int fg = lane >> 4;            // 0..3
    const int wm = wid >> 1;             // 0..3 -> n-range wm*64
    const int wo = wid & 1;              // 0..1 -> o-range o0 + wo*16

    const char* xb_bytes = (const char*)xb;
    const int kbase = khalf * kspan;

    f32x4 acc[4] = {};

    auto STAGE = [&](int t) {
        char* buf = smem + (t % NBUF) * BUF_BYTES;
        // A: 32 KB from pre-swizzled xb, linear copy (4 x 16B per thread)
        const char* gA = xb_bytes + (size_t)(kt0 + t) * AS_BYTES + wid * 1024 + lane * 16;
        char* lA = buf + wid * 1024;
        #pragma unroll
        for (int p = 0; p < 4; ++p) {
            __builtin_amdgcn_global_load_lds(
                (const __attribute__((address_space(1))) uint32_t*)(gA + p * 8192),
                (__attribute__((address_space(3))) uint32_t*)(lA + p * 8192), 16, 0, 0);
        }
        // B: 8 KB f32 T-tile [64][32], linear (1 x 16B per thread)
        const float* gB = Tm + (size_t)(kbase + t * 64 + wid * 8 + (lane >> 3)) * O_DIM
                              + o0 + (lane & 7) * 4;
        char* lB = buf + AS_BYTES + wid * 1024;
        __builtin_amdgcn_global_load_lds(
            (const __attribute__((address_space(1))) uint32_t*)gB,
            (__attribute__((address_space(3))) uint32_t*)lB, 16, 0, 0);
    };

    STAGE(0);
    STAGE(1);

    for (int t = 0; t < nk; ++t) {
        if (t < nk - 1) asm volatile("s_waitcnt vmcnt(5)" ::: "memory");
        else            asm volatile("s_waitcnt vmcnt(0)" ::: "memory");
        __builtin_amdgcn_s_barrier();
        if (t + 2 < nk) STAGE(t + 2);

        const char*  As = smem + (t % NBUF) * BUF_BYTES;
        const float* Bs = (const float*)(As + AS_BYTES);

        #pragma unroll
        for (int kk = 0; kk < 2; ++kk) {
            // B fragment: B[k = kk*32 + fg*8 + i][o = wo*16 + fr]
            bf16x8 b;
            #pragma unroll
            for (int i = 0; i < 8; ++i)
                b[i] = (__bf16)Bs[(kk * 32 + fg * 8 + i) * 32 + wo * 16 + fr];
            // A fragments (swizzled slot) + MFMA
            const int swz = (((kk * 4 + fg) ^ (fr & 7)) << 4);
            #pragma unroll
            for (int mi = 0; mi < 4; ++mi) {
                const int n = wm * 64 + mi * 16 + fr;
                bf16x8 a = *reinterpret_cast<const bf16x8*>(As + n * 128 + swz);
                acc[mi] = __builtin_amdgcn_mfma_f32_16x16x32_bf16(a, b, acc[mi], 0, 0, 0);
            }
        }
    }

    // epilogue: D[row = n][col = o] -> dst[o*256 + n]; 4 consecutive n per lane
    const int o = o0 + wo * 16 + fr;
    #pragma unroll
    for (int mi = 0; mi < 4; ++mi) {
        const int nbase = wm * 64 + mi * 16 + fg * 4;
        *reinterpret_cast<f32x4*>(&dst[o * N_ROWS + nbase]) = acc[mi];
    }
}

// ---------------------------------------------------------------------------
// Pairwise: o_b[j,f] = sum_i exp(-sum_d |M[i,f,d] - M[j,f,d]|)
// M reconstructed as Mt0 (+ Mt1 if split-K). grid (128 f, 4 j-quarters).
// ---------------------------------------------------------------------------
__global__ __launch_bounds__(256, 2) void pairwise_kernel(const float* __restrict__ Mt0,
                                                          const float* __restrict__ Mt1,
                                                          float* __restrict__ out) {
    __shared__ float Mf[256][36];
    __shared__ float part[4][64];

    const int f    = blockIdx.x;
    const int jq   = blockIdx.y;
    const int tid  = threadIdx.x;
    const int lane = tid & 63;
    const int wid  = tid >> 6;

    {
        float tmp[32];
        #pragma unroll
        for (int d = 0; d < 32; ++d)
            tmp[d] = Mt0[(f * KD + d) * N_ROWS + tid];
        if (Mt1 != nullptr) {
            #pragma unroll
            for (int d = 0; d < 32; ++d)
                tmp[d] += Mt1[(f * KD + d) * N_ROWS + tid];
        }
        #pragma unroll
        for (int d4 = 0; d4 < 8; ++d4) {
            f32x4 v = { tmp[d4 * 4], tmp[d4 * 4 + 1], tmp[d4 * 4 + 2], tmp[d4 * 4 + 3] };
            *reinterpret_cast<f32x4*>(&Mf[tid][d4 * 4]) = v;
        }
    }
    __syncthreads();

    const int j = jq * 64 + lane;
    float mj[32];
    #pragma unroll
    for (int d4 = 0; d4 < 8; ++d4) {
        f32x4 v = *reinterpret_cast<const f32x4*>(&Mf[j][d4 * 4]);
        mj[d4 * 4]     = v[0];
        mj[d4 * 4 + 1] = v[1];
        mj[d4 * 4 + 2] = v[2];
        mj[d4 * 4 + 3] = v[3];
    }

    float acc = 0.f;
    const int i0 = wid * 64;
    for (int ii = 0; ii < 64; ++ii) {
        const int i = i0 + ii;
        float norm = 0.f;
        #pragma unroll
        for (int d4 = 0; d4 < 8; ++d4) {
            f32x4 v = *reinterpret_cast<const f32x4*>(&Mf[i][d4 * 4]);
            norm += fabsf(v[0] - mj[d4 * 4]);
            norm += fabsf(v[1] - mj[d4 * 4 + 1]);
            norm += fabsf(v[2] - mj[d4 * 4 + 2]);
            norm += fabsf(v[3] - mj[d4 * 4 + 3]);
        }
        acc += __expf(-norm);
    }

    part[wid][lane] = acc;
    __syncthreads();
    if (tid < 64) {
        float s = part[0][tid] + part[1][tid] + part[2][tid] + part[3][tid];
        const int jj = jq * 64 + tid;
        out[jj * OUT_COLS + IN_F + f] = s;
    }
}

extern "C" void kernel_launch(void* const* d_in, const int* in_sizes, int n_in,
                              void* d_out, int out_size, void* d_ws, size_t ws_size,
                              hipStream_t stream) {
    const float* x  = (const float*)d_in[0];   // [256, 2048] f32
    const float* Tm = (const float*)d_in[1];   // [2048, 4096] f32
    float* out = (float*)d_out;                // [256, 2176] f32
    char*  ws  = (char*)d_ws;

    __bf16* xb  = (__bf16*)ws;                        // 1 MB swizzled bf16 x
    float*  Mt0 = (float*)(ws + (1 << 20));           // 4 MB partial 0
    float*  Mt1 = (float*)(ws + (1 << 20) + (4 << 20)); // 4 MB partial 1

    const size_t need_split = (size_t)(1 << 20) + 2u * (4 << 20);
    const int nsplit = (ws_size >= need_split) ? 2 : 1;
    const int kspan  = IN_F / nsplit;

    prep_kernel<<<dim3(256), 256, 0, stream>>>(x, out, xb);
    gemm_kernel<<<dim3(128, nsplit), 512, LDS_TOTAL, stream>>>(xb, Tm, Mt0, kspan);
    pairwise_kernel<<<dim3(128, 4), 256, 0, stream>>>(Mt0, nsplit == 2 ? Mt1 : nullptr, out);
}